// Round 1
// baseline (1560.310 us; speedup 1.0000x reference)
//
#include <hip/hip_runtime.h>
#include <stdint.h>

#define NA 50000          // atoms
#define DD 256            // embedding
#define NF 4              // formulas
#define NG 50000          // groundings (cliques) per formula
#define AA 3              // atoms per clique
#define MM (NG * AA)      // 150000 rows per formula
#define KK 512            // 2*D
#define BM 96             // divisible by 3 -> clique groups never split across tiles
#define BN 128
#define BK 64
#define MT ((MM + BM - 1) / BM)   // 1563

typedef __attribute__((ext_vector_type(8))) short s16x8;
typedef __attribute__((ext_vector_type(4))) float f32x4;

__device__ __forceinline__ unsigned short f2bf(float f) {
  union { float f; uint32_t u; } v; v.f = f;
  return (unsigned short)((v.u + 0x7FFFu + ((v.u >> 16) & 1u)) >> 16);  // RNE
}

__device__ __forceinline__ void gld_lds16(const void* g, void* l) {
  // async 16B/lane global->LDS; LDS dest = uniform base + lane*16, global src per-lane
  __builtin_amdgcn_global_load_lds(
      (const __attribute__((address_space(1))) uint32_t*)g,
      (__attribute__((address_space(3))) uint32_t*)l, 16, 0, 0);
}

// f32 -> bf16, 4 elems/thread
__global__ void cvt_f32_bf16(const float* __restrict__ src, unsigned short* __restrict__ dst, int n4) {
  int i = blockIdx.x * 256 + threadIdx.x;
  if (i < n4) {
    const float4 v = ((const float4*)src)[i];
    union { unsigned short s[4]; uint2 u; } o;
    o.s[0] = f2bf(v.x); o.s[1] = f2bf(v.y); o.s[2] = f2bf(v.z); o.s[3] = f2bf(v.w);
    ((uint2*)dst)[i] = o.u;
  }
}

// Build transposed bf16 weights:
// Wt0[f][n][k], n in [0,512): n<256 -> W_M[0,f,k,n], else W_U[0,f,k,n-256]
// Wt1[f][n][k], n in [0,256): W_U[1,f,k,n]
__global__ void prep_w(const float* __restrict__ WM, const float* __restrict__ WU,
                       unsigned short* __restrict__ Wt0, unsigned short* __restrict__ Wt1) {
  const int total0 = NF * 512 * 512;           // 1048576
  const int total1 = NF * 256 * 512;           // 524288
  int t = blockIdx.x * 256 + threadIdx.x;
  if (t < total0) {
    int f = t >> 18;                            // /(512*512)
    int n = (t >> 9) & 511;
    int k = t & 511;
    float v = (n < 256) ? WM[(((size_t)f) * 512 + k) * 256 + n]
                        : WU[(((size_t)f) * 512 + k) * 256 + (n - 256)];
    Wt0[t] = f2bf(v);
  } else if (t < total0 + total1) {
    int e = t - total0;
    int f = e >> 17;                            // /(256*512)
    int n = (e >> 9) & 255;
    int k = e & 511;
    float v = WU[(((size_t)(NF + f)) * 512 + k) * 256 + n];  // W_U[1,f,k,n]
    Wt1[e] = f2bf(v);
  }
}

// Fused gather-GEMM with per-layer epilogue.
// A row m (global r = m0+m): cols 0..255 from atomSrc[gIdx[f,r]], cols 256..511 from gclSrc[f, r/3]
// B = Wt[f] stored [NOUT][512] bf16 (transposed) so B-fragments are contiguous.
template <int LAYER>
__global__ __launch_bounds__(256, 2)
void fgnn_gemm(const unsigned short* __restrict__ atomSrc,
               const unsigned short* __restrict__ gclSrc,
               const unsigned short* __restrict__ Wt,
               const int* __restrict__ gIdx,
               const float* __restrict__ bM,
               const float* __restrict__ bU,
               float* __restrict__ atomOut,          // f32 scatter-max target (u32 atomics)
               unsigned short* __restrict__ gclOut)  // bf16 [F*G][256] (layer 0, nt<2)
{
  constexpr int NOUT = (LAYER == 0) ? 512 : 256;
  const int mt = blockIdx.x, nt = blockIdx.y, f = blockIdx.z;
  const int m0 = mt * BM;
  const int tid = threadIdx.x;
  const int lane = tid & 63, wid = tid >> 6;
  const int wm = wid >> 1, wn = wid & 1;   // 2x2 wave grid: 48 rows x 64 cols per wave

  __shared__ union U {
    struct { unsigned short A[2][BM * BK]; unsigned short B[2][BN * BK]; } s;  // 24KB + 32KB
    float gc[BM * BN];                                                          // 48KB epilogue reuse
  } u;
  __shared__ int idx_lds[BM];

  if (tid < BM) {
    int r = m0 + tid; if (r > MM - 1) r = MM - 1;
    idx_lds[tid] = gIdx[(size_t)f * MM + r];
  }
  __syncthreads();

  // ---- staging source pointers (XOR chunk swizzle applied on the GLOBAL side; LDS dest linear) ----
  // LDS layout per tile: row-major [rows][BK], 16B chunk c at phys slot (c ^ (row&7)).
  const unsigned short* paA[3];  // atom half (k0 < 256): + k0
  const unsigned short* paG[3];  // gcl half  (k0 >= 256): + (k0-256)
#pragma unroll
  for (int i = 0; i < 3; ++i) {
    int row = wid * 8 + i * 32 + (lane >> 3);       // 0..95
    int c = (lane & 7) ^ (row & 7);                  // logical chunk for phys slot lane&7
    int r = m0 + row; if (r > MM - 1) r = MM - 1;
    int idx = idx_lds[row];
    int g = r / 3;
    paA[i] = atomSrc + (size_t)idx * DD + c * 8;
    paG[i] = gclSrc + ((size_t)f * NG + g) * DD + c * 8;
  }
  const unsigned short* pB[4];
#pragma unroll
  for (int i = 0; i < 4; ++i) {
    int nrow = wid * 8 + i * 32 + (lane >> 3);      // 0..127
    int c = (lane & 7) ^ (nrow & 7);
    pB[i] = Wt + ((size_t)f * NOUT + (size_t)nt * BN + nrow) * KK + c * 8;
  }

  auto stage = [&](int buf, int k0) {
#pragma unroll
    for (int i = 0; i < 3; ++i) {
      const unsigned short* src = (k0 < DD) ? (paA[i] + k0) : (paG[i] + (k0 - DD));
      gld_lds16(src, &u.s.A[buf][i * 2048 + wid * 512]);
    }
#pragma unroll
    for (int i = 0; i < 4; ++i)
      gld_lds16(pB[i] + k0, &u.s.B[buf][i * 2048 + wid * 512]);
  };

  f32x4 acc[3][4];
#pragma unroll
  for (int m = 0; m < 3; ++m)
#pragma unroll
    for (int n = 0; n < 4; ++n) acc[m][n] = (f32x4)0.f;

  stage(0, 0);
  int cur = 0;
  for (int ks = 0; ks < KK / BK; ++ks) {
    __syncthreads();                                  // drains vmcnt: buf[cur] staged & prior reads done
    if (ks + 1 < KK / BK) stage(cur ^ 1, (ks + 1) * BK);
#pragma unroll
    for (int kk = 0; kk < 2; ++kk) {
      s16x8 af[3], bf4[4];
#pragma unroll
      for (int m = 0; m < 3; ++m) {
        int row = wm * 48 + m * 16 + (lane & 15);
        int c = kk * 4 + (lane >> 4);
        af[m] = *(const s16x8*)&u.s.A[cur][row * BK + ((c ^ (row & 7)) << 3)];
      }
#pragma unroll
      for (int n = 0; n < 4; ++n) {
        int nr = wn * 64 + n * 16 + (lane & 15);
        int c = kk * 4 + (lane >> 4);
        bf4[n] = *(const s16x8*)&u.s.B[cur][nr * BK + ((c ^ (nr & 7)) << 3)];
      }
#pragma unroll
      for (int m = 0; m < 3; ++m)
#pragma unroll
        for (int n = 0; n < 4; ++n)
          acc[m][n] = __builtin_amdgcn_mfma_f32_16x16x32_bf16(af[m], bf4[n], acc[m][n], 0, 0, 0);
    }
    cur ^= 1;
  }

  // ---- epilogue ----
  if (LAYER == 0 && nt < 2) {
    // message path: relu(+b_M) -> max over the 3 rows of each clique -> gclOut (bf16, plain stores)
    float bias_n[4];
#pragma unroll
    for (int n = 0; n < 4; ++n)
      bias_n[n] = bM[f * DD + nt * BN + wn * 64 + n * 16 + (lane & 15)];
    __syncthreads();                                  // done with staging LDS
#pragma unroll
    for (int m = 0; m < 3; ++m)
#pragma unroll
      for (int n = 0; n < 4; ++n) {
        int col = wn * 64 + n * 16 + (lane & 15);
#pragma unroll
        for (int r = 0; r < 4; ++r) {
          int row = wm * 48 + m * 16 + ((lane >> 4) << 2) + r;  // C/D: col=lane&15, row=(lane>>4)*4+reg
          u.gc[row * BN + col] = fmaxf(acc[m][n][r] + bias_n[n], 0.f);
        }
      }
    __syncthreads();
    int nvg = ((MM - m0 < BM) ? (MM - m0) : BM) / 3;
    for (int e = tid; e < 32 * BN; e += 256) {
      int grp = e >> 7, col = e & 127;
      if (grp < nvg) {
        float v = fmaxf(fmaxf(u.gc[(grp * 3 + 0) * BN + col],
                              u.gc[(grp * 3 + 1) * BN + col]),
                        u.gc[(grp * 3 + 2) * BN + col]);
        gclOut[((size_t)f * NG + (size_t)(m0 / 3 + grp)) * DD + nt * BN + col] = f2bf(v);
      }
    }
  } else {
    // update path: relu(+b_U) -> scatter-max into atomOut via u32 atomicMax (values >= 0)
    const float* bp; int coloff;
    if (LAYER == 0) { bp = bU + f * DD;        coloff = (nt - 2) * BN; }
    else            { bp = bU + (NF + f) * DD; coloff = nt * BN; }
    float bias_n[4];
#pragma unroll
    for (int n = 0; n < 4; ++n)
      bias_n[n] = bp[coloff + wn * 64 + n * 16 + (lane & 15)];
#pragma unroll
    for (int m = 0; m < 3; ++m)
#pragma unroll
      for (int r = 0; r < 4; ++r) {
        int rl = wm * 48 + m * 16 + ((lane >> 4) << 2) + r;
        if (m0 + rl < MM) {
          int idx = idx_lds[rl];
#pragma unroll
          for (int n = 0; n < 4; ++n) {
            int col = coloff + wn * 64 + n * 16 + (lane & 15);
            float v = fmaxf(acc[m][n][r] + bias_n[n], 0.f);
            atomicMax((unsigned int*)&atomOut[(size_t)idx * DD + col], __float_as_uint(v));
          }
        }
      }
  }
}

extern "C" void kernel_launch(void* const* d_in, const int* in_sizes, int n_in,
                              void* d_out, int out_size, void* d_ws, size_t ws_size,
                              hipStream_t stream) {
  const float* x  = (const float*)d_in[0];
  const int*   gi = (const int*)d_in[1];
  const float* fg = (const float*)d_in[2];
  const float* WM = (const float*)d_in[3];
  const float* bM = (const float*)d_in[4];
  const float* WU = (const float*)d_in[5];
  const float* bU = (const float*)d_in[6];
  float* out = (float*)d_out;

  char* ws = (char*)d_ws;
  size_t off = 0;
  auto alloc = [&](size_t b) { char* p = ws + off; off += (b + 255) & ~(size_t)255; return p; };
  unsigned short* gcl0  = (unsigned short*)alloc((size_t)NF * NG * DD * 2);   // 102.4 MB
  unsigned short* gcl1  = (unsigned short*)alloc((size_t)NF * NG * DD * 2);   // 102.4 MB
  unsigned short* atomB = (unsigned short*)alloc((size_t)NA * DD * 2);        // 25.6 MB
  unsigned short* Wt0   = (unsigned short*)alloc((size_t)NF * 512 * 512 * 2); // 2 MB
  unsigned short* Wt1   = (unsigned short*)alloc((size_t)NF * 256 * 512 * 2); // 1 MB

  // d_out doubles as the f32 layer-0 scatter target (atom1), then is re-zeroed for layer 1.
  hipMemsetAsync(d_out, 0, (size_t)NA * DD * 4, stream);

  cvt_f32_bf16<<<(NA * DD / 4 + 255) / 256, 256, 0, stream>>>(x, atomB, NA * DD / 4);
  cvt_f32_bf16<<<(NF * NG * DD / 4 + 255) / 256, 256, 0, stream>>>(fg, gcl0, NF * NG * DD / 4);
  prep_w<<<((NF * 512 * 512 + NF * 256 * 512) + 255) / 256, 256, 0, stream>>>(WM, WU, Wt0, Wt1);

  fgnn_gemm<0><<<dim3(MT, 4, NF), 256, 0, stream>>>(atomB, gcl0, Wt0, gi, bM, bU, out, gcl1);

  cvt_f32_bf16<<<(NA * DD / 4 + 255) / 256, 256, 0, stream>>>(out, atomB, NA * DD / 4);  // atom1 -> bf16
  hipMemsetAsync(d_out, 0, (size_t)NA * DD * 4, stream);

  fgnn_gemm<1><<<dim3(MT, 2, NF), 256, 0, stream>>>(atomB, gcl1, Wt1, gi, bM, bU, out, nullptr);
}